// Round 1
// baseline (569.919 us; speedup 1.0000x reference)
//
#include <hip/hip_runtime.h>
#include <math.h>

#define NN 256        // num spins
#define DIMF 64       // feature dim
#define BATCH 64      // real batches
#define PB 4          // pseudo batches carrying identity columns (for traces)
#define NB (BATCH + PB)   // 68
#define KMAX 20       // highest power J^k used
#define NM (KMAX + 1) // moments m_0..m_20
#define YSZ (NN * DIMF)   // 16384 floats per batch slab

// ---------------------------------------------------------------------------
// init: build J = 0.5*(Jr + Jr^T) with zero diagonal; Y0 = [x | identity
// chunks]; zero the moment accumulator array.
// ---------------------------------------------------------------------------
__global__ void init_kernel(const float* __restrict__ x,
                            const float* __restrict__ Jr,
                            float* __restrict__ J,
                            float* __restrict__ Yh,
                            float* __restrict__ m) {
    int idx = blockIdx.x * blockDim.x + threadIdx.x;
    int stride = gridDim.x * blockDim.x;
    const int total = NB * YSZ;   // 1114112 (largest section)
    for (int i = idx; i < total; i += stride) {
        if (i < NN * NN) {
            int r = i >> 8, c = i & 255;
            float v = 0.5f * (Jr[r * NN + c] + Jr[c * NN + r]);
            J[i] = (r == c) ? 0.0f : v;
        }
        int b = i / YSZ;
        int rem = i - b * YSZ;
        int row = rem >> 6;    // spin index 0..255
        int f = rem & 63;      // feature index 0..63
        float v;
        if (b < BATCH) v = x[i];                      // x layout identical
        else v = (row == ((b - BATCH) * DIMF + f)) ? 1.0f : 0.0f;
        Yh[i] = v;
        if (i < NB * NM) m[i] = 0.0f;
    }
}

// ---------------------------------------------------------------------------
// m0: m[b][0] = sum(Y0[b]^2)  (for pseudo batches this gives 64 -> T0=256)
// ---------------------------------------------------------------------------
__global__ void m0_kernel(const float* __restrict__ Yh, float* __restrict__ m) {
    __shared__ float red[256];
    int b = blockIdx.x;
    const float* y = Yh + b * YSZ;
    float s = 0.f;
    for (int i = threadIdx.x; i < YSZ; i += 256) { float v = y[i]; s += v * v; }
    red[threadIdx.x] = s;
    __syncthreads();
    for (int o = 128; o > 0; o >>= 1) {
        if (threadIdx.x < o) red[threadIdx.x] += red[threadIdx.x + o];
        __syncthreads();
    }
    if (threadIdx.x == 0) m[b * NM + 0] = red[0];
}

// ---------------------------------------------------------------------------
// chain: Yout[b] = J * Yin[b]  (256x64 = 256x256 * 256x64), fused epilogue
// accumulates m[b][k] += <Yh[b], Yout[b]>.
// grid = (4 row-tiles, NB batches), block = 256 threads.
// Each block computes a 64x64 output tile; each thread owns 4x4 outputs.
// ---------------------------------------------------------------------------
__global__ __launch_bounds__(256)
void chain_kernel(const float* __restrict__ J,
                  const float* __restrict__ Yin,
                  float* __restrict__ Yout,
                  const float* __restrict__ Yh,
                  float* __restrict__ m, int k) {
    __shared__ float Jt[64][17];   // [row][jj], +1 pad
    __shared__ float Yt[16][64];   // [jj][f]
    __shared__ float red[256];
    const int tile = blockIdx.x;       // row tile 0..3
    const int b = blockIdx.y;          // batch 0..67
    const int t = threadIdx.x;
    const int i0 = tile * 64;
    const float* Yb = Yin + b * YSZ;
    const int tr = t >> 4;             // 0..15 -> rows tr*4..tr*4+3
    const int tc = t & 15;             // 0..15 -> cols tc*4..tc*4+3

    float acc[4][4] = {};

    for (int j0 = 0; j0 < NN; j0 += 16) {
        // stage J tile (64 rows x 16 k)
        #pragma unroll
        for (int l = 0; l < 4; ++l) {
            int idx = l * 256 + t;           // 0..1023
            int r = idx >> 4, jj = idx & 15;
            Jt[r][jj] = J[(i0 + r) * NN + j0 + jj];
        }
        // stage Y tile (16 k x 64 f)
        #pragma unroll
        for (int l = 0; l < 4; ++l) {
            int idx = l * 256 + t;
            int jj = idx >> 6, f = idx & 63;
            Yt[jj][f] = Yb[(j0 + jj) * DIMF + f];
        }
        __syncthreads();
        #pragma unroll
        for (int jj = 0; jj < 16; ++jj) {
            float yv[4];
            #pragma unroll
            for (int c = 0; c < 4; ++c) yv[c] = Yt[jj][tc * 4 + c];
            #pragma unroll
            for (int a = 0; a < 4; ++a) {
                float jv = Jt[tr * 4 + a][jj];
                #pragma unroll
                for (int c = 0; c < 4; ++c) acc[a][c] += jv * yv[c];
            }
        }
        __syncthreads();
    }

    // write tile + fused dot with h (= Yh slab, identity for pseudo batches)
    float part = 0.f;
    float* Yo = Yout + b * YSZ;
    const float* Hb = Yh + b * YSZ;
    #pragma unroll
    for (int a = 0; a < 4; ++a) {
        int gi = i0 + tr * 4 + a;          // global row 0..255
        int off = gi * DIMF + tc * 4;
        float4 v = make_float4(acc[a][0], acc[a][1], acc[a][2], acc[a][3]);
        *(float4*)(Yo + off) = v;
        float4 h4 = *(const float4*)(Hb + off);
        part += acc[a][0] * h4.x + acc[a][1] * h4.y + acc[a][2] * h4.z + acc[a][3] * h4.w;
    }
    red[t] = part;
    __syncthreads();
    for (int o = 128; o > 0; o >>= 1) {
        if (t < o) red[t] += red[t + o];
        __syncthreads();
    }
    if (t == 0) atomicAdd(&m[b * NM + k], red[0]);
}

// ---------------------------------------------------------------------------
// solve: per-batch scalar Newton (40 iters, |f|>1e-4 gate) on the moment
// series, then phi and afe. Traces T_k = sum of the 4 pseudo-batch moments.
// out[0..63] = afe, out[64..127] = t_star.
// ---------------------------------------------------------------------------
__global__ void solve_kernel(const float* __restrict__ m, float* __restrict__ out) {
    int b = blockIdx.x * blockDim.x + threadIdx.x;
    if (b >= BATCH) return;
    double mk[NM], Tk[NM];
    for (int k = 0; k < NM; ++k) {
        mk[k] = (double)m[b * NM + k];
        double tk = 0.0;
        for (int p = 0; p < PB; ++p) tk += (double)m[(BATCH + p) * NM + k];
        Tk[k] = tk;
    }
    double t = 1.0;
    for (int it = 0; it < 40; ++it) {
        double inv = 1.0 / t;
        double p1 = inv;           // 1/t^{k+1}
        double S1 = 0, S3 = 0, S1d = 0, S3d = 0;
        for (int k = 0; k < NM; ++k) {
            double p2 = p1 * inv;  // 1/t^{k+2}
            double p3 = p2 * inv;  // 1/t^{k+3}
            S1  += Tk[k] * p1;
            S1d += (double)(k + 1) * Tk[k] * p2;
            S3  += (double)(k + 1) * mk[k] * p2;
            S3d += (double)(k + 1) * (k + 2) * mk[k] * p3;
            p1 = p2;
        }
        double f  = 256.0 - 0.5 * S1 - S3 * (1.0 / 256.0);
        double df = 0.5 * S1d + S3d * (1.0 / 256.0);
        if (fabs(f) > 1e-4) t -= f / df;
    }
    // phi at t*
    double inv = 1.0 / t;
    double logdet = 256.0 * log(t);
    double quad = 0.0;
    double p1 = inv;   // 1/t^{k+1}
    double pk = 1.0;   // 1/t^k
    for (int k = 0; k < NM; ++k) {
        quad += mk[k] * p1;
        if (k >= 1) {
            pk *= inv;
            logdet -= Tk[k] / (double)k * pk;
        }
        p1 *= inv;
    }
    double phi = 256.0 * t - 0.5 * logdet + quad * (1.0 / 256.0);
    double afe = -(0.5 * log(M_PI) + phi * (1.0 / 256.0));
    out[b] = (float)afe;
    out[BATCH + b] = (float)t;
}

// ---------------------------------------------------------------------------
extern "C" void kernel_launch(void* const* d_in, const int* in_sizes, int n_in,
                              void* d_out, int out_size, void* d_ws, size_t ws_size,
                              hipStream_t stream) {
    const float* x  = (const float*)d_in[0];   // (64,256,64) fp32
    const float* Jr = (const float*)d_in[1];   // (256,256) fp32
    float* out = (float*)d_out;                // 128 fp32: afe(64) ++ t_star(64)
    float* ws = (float*)d_ws;

    float* J  = ws;                  // 65536
    float* Yh = J + NN * NN;         // NB*YSZ
    float* Ya = Yh + NB * YSZ;
    float* Yb = Ya + NB * YSZ;
    float* m  = Yb + NB * YSZ;       // NB*NM

    init_kernel<<<1024, 256, 0, stream>>>(x, Jr, J, Yh, m);
    m0_kernel<<<NB, 256, 0, stream>>>(Yh, m);

    const float* in = Yh;
    float* bufs[2] = {Ya, Yb};
    for (int k = 1; k <= KMAX; ++k) {
        float* ob = bufs[(k - 1) & 1];
        chain_kernel<<<dim3(4, NB), 256, 0, stream>>>(J, in, ob, Yh, m, k);
        in = ob;
    }
    solve_kernel<<<1, 64, 0, stream>>>(m, out);
}

// Round 2
// 150.018 us; speedup vs baseline: 3.7990x; 3.7990x over previous
//
#include <hip/hip_runtime.h>
#include <math.h>

#define NN 256
#define DIMF 64
#define BATCH 64
#define PB 4
#define NB (BATCH + PB)     // 68
#define KMAX 12             // moments m_0..m_12 (tail ~1e-9 in afe)
#define NM (KMAX + 1)
#define NSTEPS (KMAX / 2)   // 6 chain steps
#define SLAB (DIMF * NN)    // 16384 bf16 elems per slab (n-major: [n][k])

using short8 = __attribute__((ext_vector_type(8))) short;
using f32x4  = __attribute__((ext_vector_type(4))) float;

__device__ __forceinline__ float bf2f(unsigned short u) {
    union { unsigned int i; float f; } v; v.i = ((unsigned int)u) << 16; return v.f;
}
__device__ __forceinline__ unsigned short f2bf(float f) {
    union { float f; unsigned int i; } v; v.f = f;
    unsigned int b = v.i;
    return (unsigned short)((b + 0x7FFFu + ((b >> 16) & 1u)) >> 16);
}

// ---------------------------------------------------------------------------
// init: J bf16 (symmetrized, traceless); Y0 slabs n-major bf16
// (real: YT[b][n][k] = x[b][k][n]; pseudo p: identity column 64p+n); zero m.
// ---------------------------------------------------------------------------
__global__ void init_kernel(const float* __restrict__ x,
                            const float* __restrict__ Jr,
                            unsigned short* __restrict__ Jb,
                            unsigned short* __restrict__ Y0,
                            float* __restrict__ m) {
    int i = blockIdx.x * blockDim.x + threadIdx.x;
    if (i >= NB * SLAB) return;
    if (i < NN * NN) {
        int r = i >> 8, c = i & 255;
        float v = (r == c) ? 0.0f : 0.5f * (Jr[i] + Jr[c * NN + r]);
        Jb[i] = f2bf(v);
    }
    if (i < NB * NM) m[i] = 0.0f;
    int b = i >> 14, rem = i & 16383;
    int n = rem >> 8, k = rem & 255;
    unsigned short v;
    if (b < BATCH) v = f2bf(x[(b << 14) + (k << 6) + n]);
    else v = (k == (((b - BATCH) << 6) + n)) ? (unsigned short)0x3F80 : (unsigned short)0;
    Y0[i] = v;
}

// ---------------------------------------------------------------------------
// m0: m[b][0] = ||x_b||^2 in fp32 (exact h, not bf16). grid 256 = 4 blocks/batch.
// ---------------------------------------------------------------------------
__global__ void m0_kernel(const float* __restrict__ x, float* __restrict__ m) {
    __shared__ float red[256];
    int b = blockIdx.x >> 2, q = blockIdx.x & 3;
    const float* xb = x + (b << 14) + (q << 12);
    float s = 0.f;
    for (int i = threadIdx.x; i < 4096; i += 256) { float v = xb[i]; s += v * v; }
    red[threadIdx.x] = s;
    __syncthreads();
    for (int o = 128; o > 0; o >>= 1) {
        if (threadIdx.x < o) red[threadIdx.x] += red[threadIdx.x + o];
        __syncthreads();
    }
    if (threadIdx.x == 0) atomicAdd(&m[b * NM + 0], red[0]);
}

// ---------------------------------------------------------------------------
// chain step j: Yout = J * Yin (per slab), slabs n-major bf16.
// MFMA 16x16x32 bf16, operands loaded directly from global (k-contiguous),
// no LDS staging, no K-loop barriers. Epilogue: scattered bf16 store of Yout
// + fp32 dots m[2j-1] += <Yin,Yout>, m[2j] += <Yout,Yout>.
// grid (4 row-tiles, 68 slabs), block 256 (4 waves; wave w owns m-slice w*16).
// ---------------------------------------------------------------------------
__global__ __launch_bounds__(256)
void chain_kernel(const unsigned short* __restrict__ J,
                  const unsigned short* __restrict__ Yin,
                  unsigned short* __restrict__ Yout,
                  float* __restrict__ m, int j) {
    const int b = blockIdx.y;
    const int m0 = blockIdx.x * 64;
    const int t = threadIdx.x;
    const int w = t >> 6;
    const int lane = t & 63;
    const int quad = lane >> 4;
    const int l15 = lane & 15;
    const int koff = quad * 8;

    const unsigned short* Yb = Yin + b * SLAB;
    unsigned short* Yo = Yout + b * SLAB;

    const int mrow = m0 + w * 16 + l15;
    const short8* Ap = (const short8*)(J + (mrow << 8) + koff);
    const short8* Bp[4];
#pragma unroll
    for (int nt = 0; nt < 4; ++nt)
        Bp[nt] = (const short8*)(Yb + (((nt << 4) + l15) << 8) + koff);

    f32x4 acc[4] = {};
#pragma unroll
    for (int kc = 0; kc < 8; ++kc) {
        short8 a = Ap[kc * 4];           // k = kc*32 + quad*8 + j
#pragma unroll
        for (int nt = 0; nt < 4; ++nt) {
            acc[nt] = __builtin_amdgcn_mfma_f32_16x16x32_bf16(a, Bp[nt][kc * 4], acc[nt], 0, 0, 0);
        }
    }

    // epilogue: position (row mm, col n); slab layout [n][k=mm]
    const int mbase = m0 + w * 16 + quad * 4;
    float d1 = 0.f, d2 = 0.f;
#pragma unroll
    for (int nt = 0; nt < 4; ++nt) {
        int n = (nt << 4) + l15;
#pragma unroll
        for (int r = 0; r < 4; ++r) {
            float v = acc[nt][r];
            int off = (n << 8) + mbase + r;
            Yo[off] = f2bf(v);
            d1 += bf2f(Yb[off]) * v;
            d2 += v * v;
        }
    }

    __shared__ float red[256][2];
    red[t][0] = d1; red[t][1] = d2;
    __syncthreads();
    for (int o = 128; o > 0; o >>= 1) {
        if (t < o) { red[t][0] += red[t + o][0]; red[t][1] += red[t + o][1]; }
        __syncthreads();
    }
    if (t == 0) {
        atomicAdd(&m[b * NM + 2 * j - 1], red[0][0]);
        atomicAdd(&m[b * NM + 2 * j],     red[0][1]);
    }
}

// ---------------------------------------------------------------------------
// solve: fp32 Newton with early exit (equivalent to reference's gated update),
// then phi/afe. T_k = sum of 4 pseudo-slab moments; T_0 = 256 analytic.
// ---------------------------------------------------------------------------
__global__ void solve_kernel(const float* __restrict__ m, float* __restrict__ out) {
    int b = threadIdx.x;
    if (b >= BATCH) return;
    float mk[NM], Tk[NM];
    mk[0] = m[b * NM];
    Tk[0] = 256.0f;
    for (int k = 1; k < NM; ++k) {
        mk[k] = m[b * NM + k];
        float s = 0.f;
        for (int p = 0; p < PB; ++p) s += m[(BATCH + p) * NM + k];
        Tk[k] = s;
    }
    float t = 1.0f;
    for (int it = 0; it < 40; ++it) {
        float inv = 1.0f / t;
        float p1 = inv, S1 = 0.f, S1d = 0.f, S3 = 0.f, S3d = 0.f;
        for (int k = 0; k < NM; ++k) {
            float p2 = p1 * inv;
            float p3 = p2 * inv;
            float kp1 = (float)(k + 1);
            S1  += Tk[k] * p1;
            S1d += kp1 * Tk[k] * p2;
            S3  += kp1 * mk[k] * p2;
            S3d += kp1 * (float)(k + 2) * mk[k] * p3;
            p1 = p2;
        }
        float f  = 256.0f - 0.5f * S1 - S3 * (1.0f / 256.0f);
        float df = 0.5f * S1d + S3d * (1.0f / 256.0f);
        if (fabsf(f) <= 1e-4f) break;
        t -= f / df;
    }
    float inv = 1.0f / t;
    float logdet = 256.0f * logf(t);
    float quad = 0.f;
    float p1 = inv, pk = 1.0f;
    for (int k = 0; k < NM; ++k) {
        quad += mk[k] * p1;
        if (k >= 1) { pk *= inv; logdet -= Tk[k] / (float)k * pk; }
        p1 *= inv;
    }
    float phi = 256.0f * t - 0.5f * logdet + quad * (1.0f / 256.0f);
    float afe = -(0.5f * logf((float)M_PI) + phi * (1.0f / 256.0f));
    out[b] = afe;
    out[BATCH + b] = t;
}

// ---------------------------------------------------------------------------
extern "C" void kernel_launch(void* const* d_in, const int* in_sizes, int n_in,
                              void* d_out, int out_size, void* d_ws, size_t ws_size,
                              hipStream_t stream) {
    const float* x  = (const float*)d_in[0];
    const float* Jr = (const float*)d_in[1];
    float* out = (float*)d_out;

    char* base = (char*)d_ws;
    unsigned short* Jb = (unsigned short*)base;                 // 128 KB
    unsigned short* Y0 = (unsigned short*)(base + 131072);      // 2.23 MB each
    unsigned short* Ya = Y0 + NB * SLAB;
    unsigned short* Yb = Ya + NB * SLAB;
    float* m = (float*)(Yb + NB * SLAB);                        // 68*13 floats

    init_kernel<<<(NB * SLAB + 255) / 256, 256, 0, stream>>>(x, Jr, Jb, Y0, m);
    m0_kernel<<<256, 256, 0, stream>>>(x, m);

    const unsigned short* in = Y0;
    unsigned short* bufs[2] = {Ya, Yb};
    for (int j = 1; j <= NSTEPS; ++j) {
        unsigned short* ob = bufs[(j - 1) & 1];
        chain_kernel<<<dim3(4, NB), 256, 0, stream>>>(Jb, in, ob, m, j);
        in = ob;
    }
    solve_kernel<<<1, 64, 0, stream>>>(m, out);
}

// Round 3
// 72.573 us; speedup vs baseline: 7.8531x; 2.0671x over previous
//
#include <hip/hip_runtime.h>
#include <math.h>

#define NN 256
#define DIMF 64
#define BATCH 64
#define PB 4
#define NB (BATCH + PB)     // 68 slabs (64 real + 4 identity pseudo-slabs)
#define KMAX 12             // moments m_0..m_12 (series tail ~1e-9 in afe)
#define NM (KMAX + 1)
#define NSTEPS (KMAX / 2)   // 6 fused chain steps
#define CG 2                // column groups per slab
#define CW 32               // columns per group
#define YSTR 264            // LDS row stride in bf16 elems (264*2B=528B -> 2-way bank alias, free)

using short8 = __attribute__((ext_vector_type(8))) short;
using f32x4  = __attribute__((ext_vector_type(4))) float;

__device__ __forceinline__ float bf2f(unsigned short u) {
    union { unsigned int i; float f; } v; v.i = ((unsigned int)u) << 16; return v.f;
}
__device__ __forceinline__ unsigned short f2bf(float f) {
    union { float f; unsigned int i; } v; v.f = f;
    unsigned int b = v.i;
    return (unsigned short)((b + 0x7FFFu + ((b >> 16) & 1u)) >> 16);
}

// ---------------------------------------------------------------------------
// jbuild: Jb = bf16(0.5*(Jr+Jr^T), zero diag); zero the moment accumulators.
// ---------------------------------------------------------------------------
__global__ void jbuild_kernel(const float* __restrict__ Jr,
                              unsigned short* __restrict__ Jb,
                              float* __restrict__ m) {
    int i = blockIdx.x * 256 + threadIdx.x;     // grid 256 -> 65536 threads
    int r = i >> 8, c = i & 255;
    float v = (r == c) ? 0.0f : 0.5f * (Jr[i] + Jr[(c << 8) + r]);
    Jb[i] = f2bf(v);
    if (i < NB * NM) m[i] = 0.0f;
}

// ---------------------------------------------------------------------------
// chain: one block = (column-group g, slab b). Carries its 32 columns of y
// through all 6 steps: y in LDS ping-pong (n-major [col][k], bf16), J streamed
// from L2, 16x16x32 bf16 MFMA. Fused: m0 (fp32, from x during load) and the
// per-step dots m_{2j-1}=<y_{j-1},y_j>, m_{2j}=<y_j,y_j> (wave-shfl reduce +
// atomicAdd). One __syncthreads per step.
// ---------------------------------------------------------------------------
__global__ __launch_bounds__(256)
void chain_kernel(const unsigned short* __restrict__ J,
                  const float* __restrict__ x,
                  float* __restrict__ m) {
    __shared__ unsigned short ybuf[2][CW][YSTR];
    const int g = blockIdx.x;          // 0..CG-1
    const int b = blockIdx.y;          // 0..67
    const int t = threadIdx.x;
    const int w = t >> 6;              // wave 0..3 -> rows w*64..w*64+63
    const int lane = t & 63;
    const int quad = lane >> 4;
    const int l15 = lane & 15;
    const int n0 = g * CW;

    // ---- load y0 into ybuf[0]; fuse m0 (fp32) for real slabs ----
    if (b < BATCH) {
        const float* xb = x + (b << 14) + n0;          // x[b][k][n0..]
        float s0 = 0.f;
        #pragma unroll
        for (int it = 0; it < 8; ++it) {
            int k = it * 32 + (t >> 3);
            int nn = (t & 7) * 4;
            const float4 v = *(const float4*)(xb + (k << 6) + nn);
            s0 += v.x * v.x + v.y * v.y + v.z * v.z + v.w * v.w;
            ybuf[0][nn + 0][k] = f2bf(v.x);
            ybuf[0][nn + 1][k] = f2bf(v.y);
            ybuf[0][nn + 2][k] = f2bf(v.z);
            ybuf[0][nn + 3][k] = f2bf(v.w);
        }
        #pragma unroll
        for (int o = 32; o > 0; o >>= 1) s0 += __shfl_down(s0, o);
        if (lane == 0) atomicAdd(&m[b * NM], s0);
    } else {
        int p = b - BATCH;
        for (int i = t; i < CW * 256; i += 256) ybuf[0][i >> 8][i & 255] = 0;
        __syncthreads();
        if (t < CW) ybuf[0][t][p * 64 + n0 + t] = 0x3F80;  // identity column
    }
    __syncthreads();

    int cur = 0;
    for (int j = 1; j <= NSTEPS; ++j) {
        f32x4 acc[4][2] = {};
        #pragma unroll
        for (int kc = 0; kc < 8; ++kc) {
            const int kb = kc * 32 + quad * 8;
            short8 bfrag[2];
            #pragma unroll
            for (int nt = 0; nt < 2; ++nt)
                bfrag[nt] = *(const short8*)&ybuf[cur][nt * 16 + l15][kb];
            #pragma unroll
            for (int mt = 0; mt < 4; ++mt) {
                short8 afrag = *(const short8*)(J + ((w * 64 + mt * 16 + l15) << 8) + kb);
                #pragma unroll
                for (int nt = 0; nt < 2; ++nt)
                    acc[mt][nt] = __builtin_amdgcn_mfma_f32_16x16x32_bf16(
                        afrag, bfrag[nt], acc[mt][nt], 0, 0, 0);
            }
        }

        // epilogue: dots + bf16 store into the other buffer
        const int nxt = cur ^ 1;
        float d1 = 0.f, d2 = 0.f;
        #pragma unroll
        for (int mt = 0; mt < 4; ++mt) {
            int mbase = w * 64 + mt * 16 + quad * 4;
            #pragma unroll
            for (int nt = 0; nt < 2; ++nt) {
                int col = nt * 16 + l15;
                #pragma unroll
                for (int r = 0; r < 4; ++r) {
                    float v = acc[mt][nt][r];
                    int row = mbase + r;
                    d1 += bf2f(ybuf[cur][col][row]) * v;
                    d2 += v * v;
                    ybuf[nxt][col][row] = f2bf(v);
                }
            }
        }
        #pragma unroll
        for (int o = 32; o > 0; o >>= 1) {
            d1 += __shfl_down(d1, o);
            d2 += __shfl_down(d2, o);
        }
        if (lane == 0) {
            atomicAdd(&m[b * NM + 2 * j - 1], d1);
            atomicAdd(&m[b * NM + 2 * j],     d2);
        }
        cur = nxt;
        __syncthreads();
    }
}

// ---------------------------------------------------------------------------
// solve: per-batch fp32 Newton with early exit (== reference's gated update),
// then phi/afe. T_k = sum over 4 pseudo slabs; T_0 = 256 analytic.
// ---------------------------------------------------------------------------
__global__ void solve_kernel(const float* __restrict__ m, float* __restrict__ out) {
    int b = threadIdx.x;
    if (b >= BATCH) return;
    float mk[NM], Tk[NM];
    mk[0] = m[b * NM];
    Tk[0] = 256.0f;
    for (int k = 1; k < NM; ++k) {
        mk[k] = m[b * NM + k];
        float s = 0.f;
        for (int p = 0; p < PB; ++p) s += m[(BATCH + p) * NM + k];
        Tk[k] = s;
    }
    float t = 1.0f;
    for (int it = 0; it < 40; ++it) {
        float inv = 1.0f / t;
        float p1 = inv, S1 = 0.f, S1d = 0.f, S3 = 0.f, S3d = 0.f;
        for (int k = 0; k < NM; ++k) {
            float p2 = p1 * inv;
            float p3 = p2 * inv;
            float kp1 = (float)(k + 1);
            S1  += Tk[k] * p1;
            S1d += kp1 * Tk[k] * p2;
            S3  += kp1 * mk[k] * p2;
            S3d += kp1 * (float)(k + 2) * mk[k] * p3;
            p1 = p2;
        }
        float f  = 256.0f - 0.5f * S1 - S3 * (1.0f / 256.0f);
        float df = 0.5f * S1d + S3d * (1.0f / 256.0f);
        if (fabsf(f) <= 1e-4f) break;
        t -= f / df;
    }
    float inv = 1.0f / t;
    float logdet = 256.0f * logf(t);
    float quad = 0.f;
    float p1 = inv, pk = 1.0f;
    for (int k = 0; k < NM; ++k) {
        quad += mk[k] * p1;
        if (k >= 1) { pk *= inv; logdet -= Tk[k] / (float)k * pk; }
        p1 *= inv;
    }
    float phi = 256.0f * t - 0.5f * logdet + quad * (1.0f / 256.0f);
    float afe = -(0.5f * logf((float)M_PI) + phi * (1.0f / 256.0f));
    out[b] = afe;
    out[BATCH + b] = t;
}

// ---------------------------------------------------------------------------
extern "C" void kernel_launch(void* const* d_in, const int* in_sizes, int n_in,
                              void* d_out, int out_size, void* d_ws, size_t ws_size,
                              hipStream_t stream) {
    const float* x  = (const float*)d_in[0];
    const float* Jr = (const float*)d_in[1];
    float* out = (float*)d_out;

    char* base = (char*)d_ws;
    unsigned short* Jb = (unsigned short*)base;          // 128 KB
    float* m = (float*)(base + 131072);                  // 68*13 floats

    jbuild_kernel<<<256, 256, 0, stream>>>(Jr, Jb, m);
    chain_kernel<<<dim3(CG, NB), 256, 0, stream>>>(Jb, x, m);
    solve_kernel<<<1, 64, 0, stream>>>(m, out);
}